// Round 12
// baseline (108.391 us; speedup 1.0000x reference)
//
#include <hip/hip_runtime.h>
#include <math.h>

typedef __attribute__((ext_vector_type(4))) float f32x4;
typedef __attribute__((ext_vector_type(4))) unsigned int u32x4;
typedef __attribute__((ext_vector_type(8))) short s16x8;

#define SCALE_INV_SQRT_H 0.08838834764831845f  /* 1/sqrt(128) */

__device__ __forceinline__ unsigned short f2bf(float x){
  unsigned int u = __builtin_bit_cast(unsigned int, x);
  u += 0x7fffu + ((u >> 16) & 1u);
  return (unsigned short)(u >> 16);
}
__device__ __forceinline__ float bf2f(unsigned short s){
  unsigned int u = ((unsigned int)s) << 16;
  return __builtin_bit_cast(float, u);
}

// LDS-only barrier (no vmcnt drain)
__device__ __forceinline__ void bar_lds(){
  asm volatile("s_waitcnt lgkmcnt(0)" ::: "memory");
  __builtin_amdgcn_s_barrier();
}

// ---------------- 64x128-tile NT GEMM core, software-pipelined staging ------------------
__device__ __forceinline__ void gemm_core64(
    const unsigned short* __restrict__ Ag, int lda,
    const unsigned short* __restrict__ Bg, int ldb,
    int ksteps, unsigned short* As, unsigned short* Bs, f32x4 acc[2][4])
{
  const int t = threadIdx.x, lane = t & 63, w = t >> 6;
  const int m0 = (w >> 1) * 32, n0 = (w & 1) * 64;
  const int ra_ = t >> 2, ua = (t & 3) * 2;   // A: 64 rows, 2 granules/thread
  const int rb_ = t >> 1, ub = (t & 1) * 4;   // B: 128 rows, 4 granules/thread
  u32x4 va[2], vb[4];
  {
    const unsigned short* ga = Ag + (size_t)ra_ * lda;
    const unsigned short* gb = Bg + (size_t)rb_ * ldb;
#pragma unroll
    for (int q = 0; q < 2; q++) va[q] = *(const u32x4*)(ga + (ua + q) * 8);
#pragma unroll
    for (int q = 0; q < 4; q++) vb[q] = *(const u32x4*)(gb + (ub + q) * 8);
  }
  for (int kk = 0; kk < ksteps; kk++) {
    __syncthreads();
#pragma unroll
    for (int q = 0; q < 2; q++)
      ((u32x4*)(As + ra_ * 64))[(ua + q) ^ (ra_ & 7)] = va[q];
#pragma unroll
    for (int q = 0; q < 4; q++)
      ((u32x4*)(Bs + rb_ * 64))[(ub + q) ^ (rb_ & 7)] = vb[q];
    __syncthreads();
    if (kk + 1 < ksteps) {   // issue next-step loads; in flight across MFMA
      const unsigned short* ga = Ag + (size_t)ra_ * lda + (kk + 1) * 64;
      const unsigned short* gb = Bg + (size_t)rb_ * ldb + (kk + 1) * 64;
#pragma unroll
      for (int q = 0; q < 2; q++) va[q] = *(const u32x4*)(ga + (ua + q) * 8);
#pragma unroll
      for (int q = 0; q < 4; q++) vb[q] = *(const u32x4*)(gb + (ub + q) * 8);
    }
    s16x8 af[2][2], bfr[4][2];
#pragma unroll
    for (int ks = 0; ks < 2; ks++) {
      int sa = ks * 4 + (lane >> 4);
#pragma unroll
      for (int i = 0; i < 2; i++) {
        int ra = m0 + i * 16 + (lane & 15);
        af[i][ks] = *(const s16x8*)(As + ra * 64 + ((sa ^ (ra & 7)) << 3));
      }
#pragma unroll
      for (int j = 0; j < 4; j++) {
        int rb = n0 + j * 16 + (lane & 15);
        bfr[j][ks] = *(const s16x8*)(Bs + rb * 64 + ((sa ^ (rb & 7)) << 3));
      }
    }
#pragma unroll
    for (int ks = 0; ks < 2; ks++)
#pragma unroll
      for (int i = 0; i < 2; i++)
#pragma unroll
        for (int j = 0; j < 4; j++)
          acc[i][j] = __builtin_amdgcn_mfma_f32_16x16x32_bf16(af[i][ks], bfr[j][ks], acc[i][j], 0, 0, 0);
  }
}

// ---------------- 64x64-tile NT GEMM core, software-pipelined staging -------------------
__device__ __forceinline__ void gemm_core32(
    const unsigned short* __restrict__ Ag, int lda,
    const unsigned short* __restrict__ Bg, int ldb,
    int ksteps, unsigned short* As, unsigned short* Bs, f32x4 acc[2][2])
{
  const int t = threadIdx.x, lane = t & 63, w = t >> 6;
  const int m0 = (w >> 1) * 32, n0 = (w & 1) * 32;
  const int r_ = t >> 2, u_ = (t & 3) * 2;    // 64 rows, 2 granules/thread (A and B alike)
  u32x4 va[2], vb[2];
  {
    const unsigned short* ga = Ag + (size_t)r_ * lda;
    const unsigned short* gb = Bg + (size_t)r_ * ldb;
#pragma unroll
    for (int q = 0; q < 2; q++) {
      va[q] = *(const u32x4*)(ga + (u_ + q) * 8);
      vb[q] = *(const u32x4*)(gb + (u_ + q) * 8);
    }
  }
  for (int kk = 0; kk < ksteps; kk++) {
    __syncthreads();
#pragma unroll
    for (int q = 0; q < 2; q++) {
      ((u32x4*)(As + r_ * 64))[(u_ + q) ^ (r_ & 7)] = va[q];
      ((u32x4*)(Bs + r_ * 64))[(u_ + q) ^ (r_ & 7)] = vb[q];
    }
    __syncthreads();
    if (kk + 1 < ksteps) {
      const unsigned short* ga = Ag + (size_t)r_ * lda + (kk + 1) * 64;
      const unsigned short* gb = Bg + (size_t)r_ * ldb + (kk + 1) * 64;
#pragma unroll
      for (int q = 0; q < 2; q++) {
        va[q] = *(const u32x4*)(ga + (u_ + q) * 8);
        vb[q] = *(const u32x4*)(gb + (u_ + q) * 8);
      }
    }
    s16x8 af[2][2], bfr[2][2];
#pragma unroll
    for (int ks = 0; ks < 2; ks++) {
      int sa = ks * 4 + (lane >> 4);
#pragma unroll
      for (int i = 0; i < 2; i++) {
        int ra = m0 + i * 16 + (lane & 15);
        af[i][ks] = *(const s16x8*)(As + ra * 64 + ((sa ^ (ra & 7)) << 3));
        int rb = n0 + i * 16 + (lane & 15);
        bfr[i][ks] = *(const s16x8*)(Bs + rb * 64 + ((sa ^ (rb & 7)) << 3));
      }
    }
#pragma unroll
    for (int ks = 0; ks < 2; ks++)
#pragma unroll
      for (int i = 0; i < 2; i++)
#pragma unroll
        for (int j = 0; j < 2; j++)
          acc[i][j] = __builtin_amdgcn_mfma_f32_16x16x32_bf16(af[i][ks], bfr[j][ks], acc[i][j], 0, 0, 0);
  }
}

// ---------------- 64x64 fp32->bf16 LDS-tile transpose -----------------------------------
__device__ __forceinline__ void transpose_tile(const float* __restrict__ src, int lda,
                                               unsigned short* __restrict__ dst, int ldb,
                                               int r0, int c0, unsigned short (*tile)[72])
{
  const int t = threadIdx.x;
  const int cc = (t & 15) * 4, rr = t >> 4;
#pragma unroll
  for (int j = 0; j < 4; j++) {
    int r = rr + j * 16;
    f32x4 v = *(const f32x4*)(src + (size_t)(r0 + r) * lda + c0 + cc);
#pragma unroll
    for (int q = 0; q < 4; q++) tile[r][cc + q] = f2bf(v[q]);
  }
  __syncthreads();
  const int c = t >> 2, rb = (t & 3) * 16;
  unsigned short o[16];
#pragma unroll
  for (int q = 0; q < 16; q++) o[q] = tile[rb + q][c];
  u32x4 p0, p1;
#pragma unroll
  for (int q = 0; q < 4; q++) {
    p0[q] = (unsigned)o[2 * q]     | ((unsigned)o[2 * q + 1] << 16);
    p1[q] = (unsigned)o[2 * q + 8] | ((unsigned)o[2 * q + 9] << 16);
  }
  unsigned short* dp = dst + (size_t)(c0 + c) * ldb + r0 + rb;
  *(u32x4*)dp = p0;
  *(u32x4*)(dp + 8) = p1;
}

// ---------------- K0: convert me/Wk + transpose Wq/Wv/Wo (all fp32 -> bf16) -------------
__global__ __launch_bounds__(256) void k_conv(
  const float* __restrict__ me, const float* __restrict__ Wq, const float* __restrict__ Wk,
  const float* __restrict__ Wv, const float* __restrict__ Wo,
  unsigned short* __restrict__ me_b, unsigned short* __restrict__ wk_b,
  unsigned short* __restrict__ wqt, unsigned short* __restrict__ wvt,
  unsigned short* __restrict__ wot)
{
  __shared__ unsigned short tile[64][72];
  const int bid = blockIdx.x, t = threadIdx.x;
  if (bid < 512) {
    for (int v = bid * 256 + t; v < 393216; v += 512 * 256) {
      const float* sp; unsigned short* dp;
      if (v < 262144) { sp = me + 4 * (size_t)v; dp = me_b + 4 * (size_t)v; }
      else { int i = v - 262144; sp = Wk + 4 * (size_t)i; dp = wk_b + 4 * (size_t)i; }
      f32x4 x = *(const f32x4*)sp;
      unsigned long long pk = (unsigned long long)((unsigned)f2bf(x[0]) | ((unsigned)f2bf(x[1]) << 16))
                            | (((unsigned long long)((unsigned)f2bf(x[2]) | ((unsigned)f2bf(x[3]) << 16))) << 32);
      *(unsigned long long*)dp = pk;
    }
    return;
  }
  if (bid < 640) {            // Wq: per head [512][128] -> [128][512]
    int idx = bid - 512, h = idx >> 4, tl = idx & 15;
    transpose_tile(Wq + (size_t)h * 65536, 128, wqt + (size_t)h * 65536, 512,
                   (tl >> 1) * 64, (tl & 1) * 64, tile);
  } else if (bid < 768) {     // Wv
    int idx = bid - 640, h = idx >> 4, tl = idx & 15;
    transpose_tile(Wv + (size_t)h * 65536, 128, wvt + (size_t)h * 65536, 512,
                   (tl >> 1) * 64, (tl & 1) * 64, tile);
  } else {                    // Wo: [1024][512] -> [512][1024]
    int idx = bid - 768;
    transpose_tile(Wo, 512, wot, 1024, (idx >> 3) * 64, (idx & 7) * 64, tile);
  }
}

// ---------------- K1: fused q+u, 64-row tiles, XCD-partitioned decode -------------------
// XCD x gets 2 heads x 16 bm panels: me 8MB + weights 4MB HBM total (was 18MB).
__global__ __launch_bounds__(256) void k_qu(const unsigned short* __restrict__ me_b,
                                            const unsigned short* __restrict__ wqt,
                                            const float* __restrict__ bq,
                                            const unsigned short* __restrict__ wk_b,
                                            unsigned short* __restrict__ T)
{
  __shared__ unsigned short St[2][128 * 64];   // 32 KB
  __shared__ unsigned short Qs[64 * 128];      // 16 KB
  int bid = blockIdx.x;
  // bijective: x = bid&7 (XCD), i = bid>>3 (0..63)
  // h = (x&3)*2 + (i&1); bm = (x>>2)*16 + ((i>>1)&15); bnh = (i>>5)&1
  int x = bid & 7, i = bid >> 3;
  int h = (x & 3) * 2 + (i & 1);
  int bm = (x >> 2) * 16 + ((i >> 1) & 15);
  int bnh = (i >> 5) & 1;
  const int t = threadIdx.x, lane = t & 63, w = t >> 6;
  const int m0 = (w >> 1) * 32, n0 = (w & 1) * 64;
  f32x4 z = {0.f, 0.f, 0.f, 0.f};

  // phase 1: q tile [64x128] = me[bm*64..+64) @ wqt[h]  (K=512)
  f32x4 qacc[2][4];
#pragma unroll
  for (int i2 = 0; i2 < 2; i2++) for (int j = 0; j < 4; j++) qacc[i2][j] = z;
  gemm_core64(me_b + (size_t)bm * 64 * 512, 512, wqt + (size_t)h * 65536, 512, 8, St[0], St[1], qacc);

  // issue wk chunk0 loads upfront (latency covered by Qs epilogue VALU)
  const int rb_ = t >> 1, ub = (t & 1) * 4;
  u32x4 wv[2][4];
  {
    const unsigned short* gb = wk_b + (size_t)h * 65536 + (size_t)((bnh * 2) * 128 + rb_) * 128;
#pragma unroll
    for (int kt = 0; kt < 2; kt++)
#pragma unroll
      for (int q = 0; q < 4; q++)
        wv[kt][q] = *(const u32x4*)(gb + kt * 64 + (ub + q) * 8);
  }

  // write q tile (+bq, ->bf16) into Qs
#pragma unroll
  for (int i2 = 0; i2 < 2; i2++)
#pragma unroll
    for (int j = 0; j < 4; j++) {
      int col = n0 + j * 16 + (lane & 15);
      float bqv = bq[h * 128 + col];
#pragma unroll
      for (int rg = 0; rg < 4; rg++) {
        int row = m0 + i2 * 16 + (lane >> 4) * 4 + rg;
        *(unsigned short*)((char*)Qs + row * 256 + ((((col >> 3) ^ (row & 15)) << 4)) + (col & 7) * 2)
            = f2bf(qacc[i2][j][rg] + bqv);
      }
    }
  __syncthreads();   // phase1 St reads done + Qs visible

#pragma unroll
  for (int c = 0; c < 2; c++) {
    int bn = bnh * 2 + c;
    if (c) __syncthreads();   // previous chunk's St reads done
    // write staged wk chunk regs -> LDS
#pragma unroll
    for (int kt = 0; kt < 2; kt++)
#pragma unroll
      for (int q = 0; q < 4; q++)
        ((u32x4*)(St[kt] + rb_ * 64))[(ub + q) ^ (rb_ & 7)] = wv[kt][q];
    __syncthreads();
    if (c == 0) {   // issue chunk1 loads; in flight across chunk0 MFMA
      const unsigned short* gb = wk_b + (size_t)h * 65536 + (size_t)((bnh * 2 + 1) * 128 + rb_) * 128;
#pragma unroll
      for (int kt = 0; kt < 2; kt++)
#pragma unroll
        for (int q = 0; q < 4; q++)
          wv[kt][q] = *(const u32x4*)(gb + kt * 64 + (ub + q) * 8);
    }
    // u chunk [64x128] = Qs @ wk^T  (K=128)
    f32x4 acc[2][4];
#pragma unroll
    for (int i2 = 0; i2 < 2; i2++) for (int j = 0; j < 4; j++) acc[i2][j] = z;
#pragma unroll
    for (int kt = 0; kt < 2; kt++)
#pragma unroll
      for (int ks = 0; ks < 2; ks++) {
        s16x8 af[2], bf[4];
        int sa = ks * 4 + (lane >> 4);
        int gq = (kt * 2 + ks) * 4 + (lane >> 4);
#pragma unroll
        for (int i2 = 0; i2 < 2; i2++) {
          int ra = m0 + i2 * 16 + (lane & 15);
          af[i2] = *(const s16x8*)((char*)Qs + ra * 256 + ((gq ^ (ra & 15)) << 4));
        }
#pragma unroll
        for (int j = 0; j < 4; j++) {
          int rb = n0 + j * 16 + (lane & 15);
          bf[j] = *(const s16x8*)(St[kt] + rb * 64 + ((sa ^ (rb & 7)) << 3));
        }
#pragma unroll
        for (int i2 = 0; i2 < 2; i2++)
#pragma unroll
          for (int j = 0; j < 4; j++)
            acc[i2][j] = __builtin_amdgcn_mfma_f32_16x16x32_bf16(af[i2], bf[j], acc[i2][j], 0, 0, 0);
      }
    // scaled store
#pragma unroll
    for (int i2 = 0; i2 < 2; i2++)
#pragma unroll
      for (int j = 0; j < 4; j++) {
        int col = h * 512 + bn * 128 + n0 + j * 16 + (lane & 15);
#pragma unroll
        for (int rg = 0; rg < 4; rg++) {
          int row = bm * 64 + m0 + i2 * 16 + (lane >> 4) * 4 + rg;
          T[(size_t)row * 4096 + col] = f2bf(acc[i2][j][rg] * SCALE_INV_SQRT_H);
        }
      }
  }
}

// ---------------- K2: fused per-batch attention (1 batch/block, 2048 blocks) ------------
// All 34 global loads issued upfront, nontemporal (read-once streams; keep L2 for wbuf).
__global__ __launch_bounds__(256) void k_attn(const float* __restrict__ other,
                                              const unsigned short* __restrict__ T,
                                              unsigned short* __restrict__ wbuf)
{
  __shared__ unsigned short oth[64 * 512];   // [n][kf] bf16, granule-XOR swizzled (64KB)
  __shared__ unsigned short t_lds[8 * 512];  // [h][kf] bf16, swizzled (8KB)
  __shared__ float s_lds[8 * 66];            // scores, padded
  __shared__ char a_raw[4 * 1056];           // 4 replicas of probs [8][64] bf16
  const int b = blockIdx.x;
  const int t = threadIdx.x, l = t & 63, w = t >> 6;

  // issue ALL loads upfront (nontemporal: no reuse)
  u32x4 tv[2];
  f32x4 ov[32];
  {
    const u32x4* tp = (const u32x4*)(T + (size_t)b * 4096 + (t >> 5) * 512 + (t & 31) * 16);
    tv[0] = __builtin_nontemporal_load(tp);
    tv[1] = __builtin_nontemporal_load(tp + 1);
    const f32x4* gp = (const f32x4*)(other + (size_t)b * 32768 + (size_t)(t >> 2) * 512);
#pragma unroll
    for (int j = 0; j < 32; j++) ov[j] = __builtin_nontemporal_load(gp + (t & 3) + j * 4);
  }
  // write T rows (8 x 512)
  {
    int row = t >> 5;
    int col0 = (t & 31) * 16;
#pragma unroll
    for (int i = 0; i < 2; i++) {
      int gr = (col0 >> 3) + i;
      *(u32x4*)((char*)t_lds + row * 1024 + ((gr ^ row) << 4)) = tv[i];
    }
  }
  // convert + write other (rm swizzled; b64 writes conflict-free)
  {
    int n = t >> 2;
    int nx = n & 7;
#pragma unroll
    for (int j = 0; j < 32; j++) {
      int kf0 = (t & 3) * 4 + j * 16;
      unsigned int lo = (unsigned)f2bf(ov[j][0]) | ((unsigned)f2bf(ov[j][1]) << 16);
      unsigned int hi = (unsigned)f2bf(ov[j][2]) | ((unsigned)f2bf(ov[j][3]) << 16);
      unsigned long long pk = (unsigned long long)lo | ((unsigned long long)hi << 32);
      int g = kf0 >> 3;
      *(unsigned long long*)((char*)oth + n * 1024 + ((g ^ nx) << 4) + (kf0 & 7) * 2) = pk;
    }
  }
  bar_lds();

  // GEMM1 (MFMA): S[h][n] = sum_kf T[h][kf] * other[n][kf]
  {
    f32x4 sacc = {0.f, 0.f, 0.f, 0.f};
    int arow = l & 7;
    int bn = w * 16 + (l & 15);
    int bx = bn & 7;
#pragma unroll
    for (int kk = 0; kk < 16; kk++) {
      int gr = kk * 4 + (l >> 4);
      s16x8 af  = *(const s16x8*)((char*)t_lds + arow * 1024 + ((gr ^ arow) << 4));
      s16x8 bfv = *(const s16x8*)((char*)oth + bn * 1024 + ((gr ^ bx) << 4));
      sacc = __builtin_amdgcn_mfma_f32_16x16x32_bf16(af, bfv, sacc, 0, 0, 0);
    }
    int hbase = (l >> 4) * 4;
    if (hbase < 8) {
#pragma unroll
      for (int rg = 0; rg < 4; rg++) s_lds[(hbase + rg) * 66 + w * 16 + (l & 15)] = sacc[rg];
    }
  }
  bar_lds();

  // softmax over n=64 per head; wave w handles heads 2w,2w+1; 4 prob replicas
#pragma unroll
  for (int hh = 0; hh < 2; hh++) {
    int h = w * 2 + hh;
    float v = s_lds[h * 66 + l];
    float mx = v;
#pragma unroll
    for (int off = 32; off > 0; off >>= 1) mx = fmaxf(mx, __shfl_xor(mx, off));
    float p = __expf(v - mx);
    float sm = p;
#pragma unroll
    for (int off = 32; off > 0; off >>= 1) sm += __shfl_xor(sm, off);
    unsigned short ab = f2bf(p / sm);
#pragma unroll
    for (int rep = 0; rep < 4; rep++)
      *(unsigned short*)(a_raw + rep * 1056 + h * 128 + l * 2) = ab;
  }
  bar_lds();

  // GEMM2 (VALU): w[h][kf] = sum_n a[h][n]*other[n][kf]
  {
    int g = l >> 4;
    int klane = l & 15;
    int kf0 = w * 128 + klane * 8;
    const char* abase = a_raw + g * 1056;
    s16x8 a0[8], a1[8];
#pragma unroll
    for (int r = 0; r < 8; r++) {
      a0[r] = *(const s16x8*)(abase + (2 * g) * 128 + r * 16);
      a1[r] = *(const s16x8*)(abase + (2 * g + 1) * 128 + r * 16);
    }
    float acc0[8], acc1[8];
#pragma unroll
    for (int q = 0; q < 8; q++) { acc0[q] = 0.f; acc1[q] = 0.f; }
    const char* obase = (const char*)oth;
    int gsl = w * 16 + klane;
#pragma unroll
    for (int r = 0; r < 8; r++) {
#pragma unroll
      for (int jj = 0; jj < 8; jj++) {
        int n = r * 8 + jj;
        float av0 = bf2f((unsigned short)a0[r][jj]);
        float av1 = bf2f((unsigned short)a1[r][jj]);
        s16x8 o = *(const s16x8*)(obase + n * 1024 + ((gsl ^ (n & 7)) << 4));
#pragma unroll
        for (int q = 0; q < 8; q++) {
          float f = bf2f((unsigned short)o[q]);
          acc0[q] += av0 * f;
          acc1[q] += av1 * f;
        }
      }
    }
    int h0 = 2 * g, h1 = h0 + 1;
    u32x4 p0, p1;
#pragma unroll
    for (int q = 0; q < 4; q++) {
      p0[q] = (unsigned)f2bf(acc0[2 * q]) | ((unsigned)f2bf(acc0[2 * q + 1]) << 16);
      p1[q] = (unsigned)f2bf(acc1[2 * q]) | ((unsigned)f2bf(acc1[2 * q + 1]) << 16);
    }
    *(u32x4*)(wbuf + ((size_t)b * 8 + h0) * 512 + kf0) = p0;
    *(u32x4*)(wbuf + ((size_t)b * 8 + h1) * 512 + kf0) = p1;
  }
}

// ---------------- K3: c, 64x64 tiles: 512 blocks = (bm 32 x dn 2) x (h 8); bid&7=h ------
__global__ __launch_bounds__(256) void k_c(const unsigned short* __restrict__ wbuf,
                                           const unsigned short* __restrict__ wvt,
                                           unsigned short* __restrict__ cbuf)
{
  __shared__ unsigned short As[64 * 64], Bs[64 * 64];
  int bid = blockIdx.x;
  int h = bid & 7, rest = bid >> 3;
  int dn = rest & 1, bm = rest >> 1;
  f32x4 acc[2][2]; f32x4 z = {0.f, 0.f, 0.f, 0.f};
#pragma unroll
  for (int i = 0; i < 2; i++) for (int j = 0; j < 2; j++) acc[i][j] = z;
  gemm_core32(wbuf + ((size_t)bm * 64 * 8 + h) * 512, 4096,
              wvt + (size_t)h * 65536 + (size_t)dn * 64 * 512, 512, 8, As, Bs, acc);
  // store 64x64 tile
  {
    const int t = threadIdx.x, lane = t & 63, w = t >> 6;
    const int m0 = (w >> 1) * 32, n0 = (w & 1) * 32;
    unsigned short* C = cbuf + (size_t)bm * 64 * 1024 + h * 128 + dn * 64;
#pragma unroll
    for (int i = 0; i < 2; i++)
#pragma unroll
      for (int j = 0; j < 2; j++) {
        int col = n0 + j * 16 + (lane & 15);
#pragma unroll
        for (int rg = 0; rg < 4; rg++) {
          int row = m0 + i * 16 + (lane >> 4) * 4 + rg;
          C[(size_t)row * 1024 + col] = f2bf(acc[i][j][rg]);
        }
      }
  }
}

// ---------------- K4: LN + ReLU + out = cn @ Wo  (fp32 out) ------------------------------
__global__ __launch_bounds__(256) void k_out(const unsigned short* __restrict__ cbuf,
                                             const float* __restrict__ gamma,
                                             const float* __restrict__ beta,
                                             const unsigned short* __restrict__ wot,
                                             float* __restrict__ out)
{
  __shared__ unsigned short As[32 * 1024];   // 64 KB
  __shared__ unsigned short Bs[64 * 64];     //  8 KB
  int bid = blockIdx.x;
  int bm = bid >> 3, bn = bid & 7;
  const int t = threadIdx.x, lane = t & 63, w = t >> 6;
  {
    int r = t >> 3;
    const unsigned short* g = cbuf + (size_t)(bm * 32 + r) * 1024;
#pragma unroll
    for (int q = 0; q < 16; q++) {
      int u = (t & 7) + q * 8;
      u32x4 v = *(const u32x4*)(g + u * 8);
      ((u32x4*)(As + r * 1024))[u ^ (r & 7)] = v;
    }
  }
  float gv[16], bv[16];
#pragma unroll
  for (int si = 0; si < 2; si++)
#pragma unroll
    for (int j = 0; j < 8; j++) {
      int k = (lane + si * 64) * 8 + j;
      gv[si * 8 + j] = gamma[k];
      bv[si * 8 + j] = beta[k];
    }
  __syncthreads();
  for (int rr = 0; rr < 8; rr++) {
    int r = w * 8 + rr;
    float vals[16]; float sum = 0.f, sq = 0.f;
#pragma unroll
    for (int si = 0; si < 2; si++) {
      int s = lane + si * 64;
      s16x8 pv = *(const s16x8*)(As + r * 1024 + ((s ^ (r & 7)) << 3));
#pragma unroll
      for (int j = 0; j < 8; j++) { float f = bf2f((unsigned short)pv[j]); vals[si * 8 + j] = f; sum += f; sq += f * f; }
    }
#pragma unroll
    for (int off = 32; off > 0; off >>= 1) { sum += __shfl_xor(sum, off); sq += __shfl_xor(sq, off); }
    float mu = sum * (1.f / 1024.f);
    float var = sq * (1.f / 1024.f) - mu * mu;
    float rs = rsqrtf(var + 1e-5f);
#pragma unroll
    for (int si = 0; si < 2; si++) {
      int s = lane + si * 64;
      unsigned short o[8];
#pragma unroll
      for (int j = 0; j < 8; j++) {
        float f = (vals[si * 8 + j] - mu) * rs * gv[si * 8 + j] + bv[si * 8 + j];
        o[j] = f2bf(fmaxf(f, 0.f));
      }
      u32x4 pk;
      pk[0] = (unsigned)o[0] | ((unsigned)o[1] << 16);
      pk[1] = (unsigned)o[2] | ((unsigned)o[3] << 16);
      pk[2] = (unsigned)o[4] | ((unsigned)o[5] << 16);
      pk[3] = (unsigned)o[6] | ((unsigned)o[7] << 16);
      ((u32x4*)(As + r * 1024))[s ^ (r & 7)] = pk;
    }
  }
  // GEMM: out_tile[32x64] = cn_tile @ Wo_t(bn), K=1024, pipelined Bs staging
  const int wm = w >> 1, wn = w & 1;
  f32x4 acc[2]; f32x4 z = {0.f, 0.f, 0.f, 0.f};
#pragma unroll
  for (int j = 0; j < 2; j++) acc[j] = z;
  const unsigned short* Bg = wot + (size_t)bn * 64 * 1024;
  const int rB = t >> 2, uB = (t & 3) * 2;
  u32x4 pv[2];
#pragma unroll
  for (int q = 0; q < 2; q++)
    pv[q] = *(const u32x4*)(Bg + (size_t)rB * 1024 + (uB + q) * 8);
  for (int kk = 0; kk < 16; kk++) {
    __syncthreads();
#pragma unroll
    for (int q = 0; q < 2; q++)
      ((u32x4*)(Bs + rB * 64))[(uB + q) ^ (rB & 7)] = pv[q];
    __syncthreads();
    if (kk < 15) {
#pragma unroll
      for (int q = 0; q < 2; q++)
        pv[q] = *(const u32x4*)(Bg + (size_t)rB * 1024 + (kk + 1) * 64 + (uB + q) * 8);
    }
#pragma unroll
    for (int ks = 0; ks < 2; ks++) {
      int ra = wm * 16 + (lane & 15);
      int sa = kk * 8 + ks * 4 + (lane >> 4);
      s16x8 af = *(const s16x8*)(As + ra * 1024 + ((sa ^ (ra & 7)) << 3));
      int sb = ks * 4 + (lane >> 4);
#pragma unroll
      for (int j = 0; j < 2; j++) {
        int rb = wn * 32 + j * 16 + (lane & 15);
        s16x8 bfv = *(const s16x8*)(Bs + rb * 64 + ((sb ^ (rb & 7)) << 3));
        acc[j] = __builtin_amdgcn_mfma_f32_16x16x32_bf16(af, bfv, acc[j], 0, 0, 0);
      }
    }
  }
#pragma unroll
  for (int j = 0; j < 2; j++) {
    int col = bn * 64 + wn * 32 + j * 16 + (lane & 15);
#pragma unroll
    for (int rg = 0; rg < 4; rg++) {
      int row = bm * 32 + wm * 16 + (lane >> 4) * 4 + rg;
      out[(size_t)row * 512 + col] = acc[j][rg];
    }
  }
}

// -----------------------------------------------------------------------------------------
extern "C" void kernel_launch(void* const* d_in, const int* in_sizes, int n_in,
                              void* d_out, int out_size, void* d_ws, size_t ws_size,
                              hipStream_t stream)
{
  (void)in_sizes; (void)n_in; (void)out_size;
  const float* me    = (const float*)d_in[0];
  const float* other = (const float*)d_in[1];
  const float* Wq    = (const float*)d_in[2];
  const float* bq    = (const float*)d_in[3];
  const float* Wk    = (const float*)d_in[4];
  const float* Wv    = (const float*)d_in[5];
  const float* gamma = (const float*)d_in[6];
  const float* beta  = (const float*)d_in[7];
  const float* Wo    = (const float*)d_in[8];
  float* out = (float*)d_out;
  char* ws = (char*)d_ws;

  unsigned short* me_b = (unsigned short*)(ws + 0);          //  2 MB
  unsigned short* wk_b = (unsigned short*)(ws + 2097152);    //  1 MB
  unsigned short* wqt  = (unsigned short*)(ws + 3145728);    //  1 MB
  unsigned short* wvt  = (unsigned short*)(ws + 4194304);    //  1 MB
  unsigned short* wot  = (unsigned short*)(ws + 5242880);    //  1 MB
  unsigned short* T_b  = (unsigned short*)(ws + 10485760);   // 16 MB
  unsigned short* w_b  = (unsigned short*)(ws + 27262976);   // 16 MB
  unsigned short* c_b  = (unsigned short*)(ws + 44040192);   //  4 MB
  if (ws_size < 48234496) return;

  k_conv<<<dim3(896),  dim3(256), 0, stream>>>(me, Wq, Wk, Wv, Wo, me_b, wk_b, wqt, wvt, wot);
  k_qu  <<<dim3(512),  dim3(256), 0, stream>>>(me_b, wqt, bq, wk_b, T_b);
  k_attn<<<dim3(2048), dim3(256), 0, stream>>>(other, T_b, w_b);
  k_c   <<<dim3(512),  dim3(256), 0, stream>>>(w_b, wvt, c_b);
  k_out <<<dim3(512),  dim3(256), 0, stream>>>(c_b, gamma, beta, wot, out);
}

// Round 13
// 104.207 us; speedup vs baseline: 1.0401x; 1.0401x over previous
//
#include <hip/hip_runtime.h>
#include <math.h>

typedef __attribute__((ext_vector_type(4))) float f32x4;
typedef __attribute__((ext_vector_type(4))) unsigned int u32x4;
typedef __attribute__((ext_vector_type(8))) short s16x8;

#define SCALE_INV_SQRT_H 0.08838834764831845f  /* 1/sqrt(128) */

__device__ __forceinline__ unsigned short f2bf(float x){
  unsigned int u = __builtin_bit_cast(unsigned int, x);
  u += 0x7fffu + ((u >> 16) & 1u);
  return (unsigned short)(u >> 16);
}
__device__ __forceinline__ float bf2f(unsigned short s){
  unsigned int u = ((unsigned int)s) << 16;
  return __builtin_bit_cast(float, u);
}

// LDS-only barrier (no vmcnt drain)
__device__ __forceinline__ void bar_lds(){
  asm volatile("s_waitcnt lgkmcnt(0)" ::: "memory");
  __builtin_amdgcn_s_barrier();
}

// ---------------- 64x128-tile NT GEMM core, software-pipelined staging ------------------
// Preload k=0 into regs; per step: write regs->LDS, issue k+1 loads, then frags+MFMA.
__device__ __forceinline__ void gemm_core64(
    const unsigned short* __restrict__ Ag, int lda,
    const unsigned short* __restrict__ Bg, int ldb,
    int ksteps, unsigned short* As, unsigned short* Bs, f32x4 acc[2][4])
{
  const int t = threadIdx.x, lane = t & 63, w = t >> 6;
  const int m0 = (w >> 1) * 32, n0 = (w & 1) * 64;
  const int ra_ = t >> 2, ua = (t & 3) * 2;   // A: 64 rows, 2 granules/thread
  const int rb_ = t >> 1, ub = (t & 1) * 4;   // B: 128 rows, 4 granules/thread
  u32x4 va[2], vb[4];
  {
    const unsigned short* ga = Ag + (size_t)ra_ * lda;
    const unsigned short* gb = Bg + (size_t)rb_ * ldb;
#pragma unroll
    for (int q = 0; q < 2; q++) va[q] = *(const u32x4*)(ga + (ua + q) * 8);
#pragma unroll
    for (int q = 0; q < 4; q++) vb[q] = *(const u32x4*)(gb + (ub + q) * 8);
  }
  for (int kk = 0; kk < ksteps; kk++) {
    __syncthreads();
#pragma unroll
    for (int q = 0; q < 2; q++)
      ((u32x4*)(As + ra_ * 64))[(ua + q) ^ (ra_ & 7)] = va[q];
#pragma unroll
    for (int q = 0; q < 4; q++)
      ((u32x4*)(Bs + rb_ * 64))[(ub + q) ^ (rb_ & 7)] = vb[q];
    __syncthreads();
    if (kk + 1 < ksteps) {   // issue next-step loads; in flight across MFMA
      const unsigned short* ga = Ag + (size_t)ra_ * lda + (kk + 1) * 64;
      const unsigned short* gb = Bg + (size_t)rb_ * ldb + (kk + 1) * 64;
#pragma unroll
      for (int q = 0; q < 2; q++) va[q] = *(const u32x4*)(ga + (ua + q) * 8);
#pragma unroll
      for (int q = 0; q < 4; q++) vb[q] = *(const u32x4*)(gb + (ub + q) * 8);
    }
    s16x8 af[2][2], bfr[4][2];
#pragma unroll
    for (int ks = 0; ks < 2; ks++) {
      int sa = ks * 4 + (lane >> 4);
#pragma unroll
      for (int i = 0; i < 2; i++) {
        int ra = m0 + i * 16 + (lane & 15);
        af[i][ks] = *(const s16x8*)(As + ra * 64 + ((sa ^ (ra & 7)) << 3));
      }
#pragma unroll
      for (int j = 0; j < 4; j++) {
        int rb = n0 + j * 16 + (lane & 15);
        bfr[j][ks] = *(const s16x8*)(Bs + rb * 64 + ((sa ^ (rb & 7)) << 3));
      }
    }
#pragma unroll
    for (int ks = 0; ks < 2; ks++)
#pragma unroll
      for (int i = 0; i < 2; i++)
#pragma unroll
        for (int j = 0; j < 4; j++)
          acc[i][j] = __builtin_amdgcn_mfma_f32_16x16x32_bf16(af[i][ks], bfr[j][ks], acc[i][j], 0, 0, 0);
  }
}

// ---------------- 64x64-tile NT GEMM core, software-pipelined staging -------------------
__device__ __forceinline__ void gemm_core32(
    const unsigned short* __restrict__ Ag, int lda,
    const unsigned short* __restrict__ Bg, int ldb,
    int ksteps, unsigned short* As, unsigned short* Bs, f32x4 acc[2][2])
{
  const int t = threadIdx.x, lane = t & 63, w = t >> 6;
  const int m0 = (w >> 1) * 32, n0 = (w & 1) * 32;
  const int r_ = t >> 2, u_ = (t & 3) * 2;    // 64 rows, 2 granules/thread (A and B alike)
  u32x4 va[2], vb[2];
  {
    const unsigned short* ga = Ag + (size_t)r_ * lda;
    const unsigned short* gb = Bg + (size_t)r_ * ldb;
#pragma unroll
    for (int q = 0; q < 2; q++) {
      va[q] = *(const u32x4*)(ga + (u_ + q) * 8);
      vb[q] = *(const u32x4*)(gb + (u_ + q) * 8);
    }
  }
  for (int kk = 0; kk < ksteps; kk++) {
    __syncthreads();
#pragma unroll
    for (int q = 0; q < 2; q++) {
      ((u32x4*)(As + r_ * 64))[(u_ + q) ^ (r_ & 7)] = va[q];
      ((u32x4*)(Bs + r_ * 64))[(u_ + q) ^ (r_ & 7)] = vb[q];
    }
    __syncthreads();
    if (kk + 1 < ksteps) {
      const unsigned short* ga = Ag + (size_t)r_ * lda + (kk + 1) * 64;
      const unsigned short* gb = Bg + (size_t)r_ * ldb + (kk + 1) * 64;
#pragma unroll
      for (int q = 0; q < 2; q++) {
        va[q] = *(const u32x4*)(ga + (u_ + q) * 8);
        vb[q] = *(const u32x4*)(gb + (u_ + q) * 8);
      }
    }
    s16x8 af[2][2], bfr[2][2];
#pragma unroll
    for (int ks = 0; ks < 2; ks++) {
      int sa = ks * 4 + (lane >> 4);
#pragma unroll
      for (int i = 0; i < 2; i++) {
        int ra = m0 + i * 16 + (lane & 15);
        af[i][ks] = *(const s16x8*)(As + ra * 64 + ((sa ^ (ra & 7)) << 3));
        int rb = n0 + i * 16 + (lane & 15);
        bfr[i][ks] = *(const s16x8*)(Bs + rb * 64 + ((sa ^ (rb & 7)) << 3));
      }
    }
#pragma unroll
    for (int ks = 0; ks < 2; ks++)
#pragma unroll
      for (int i = 0; i < 2; i++)
#pragma unroll
        for (int j = 0; j < 2; j++)
          acc[i][j] = __builtin_amdgcn_mfma_f32_16x16x32_bf16(af[i][ks], bfr[j][ks], acc[i][j], 0, 0, 0);
  }
}

// ---------------- 64x64 fp32->bf16 LDS-tile transpose -----------------------------------
__device__ __forceinline__ void transpose_tile(const float* __restrict__ src, int lda,
                                               unsigned short* __restrict__ dst, int ldb,
                                               int r0, int c0, unsigned short (*tile)[72])
{
  const int t = threadIdx.x;
  const int cc = (t & 15) * 4, rr = t >> 4;
#pragma unroll
  for (int j = 0; j < 4; j++) {
    int r = rr + j * 16;
    f32x4 v = *(const f32x4*)(src + (size_t)(r0 + r) * lda + c0 + cc);
#pragma unroll
    for (int q = 0; q < 4; q++) tile[r][cc + q] = f2bf(v[q]);
  }
  __syncthreads();
  const int c = t >> 2, rb = (t & 3) * 16;
  unsigned short o[16];
#pragma unroll
  for (int q = 0; q < 16; q++) o[q] = tile[rb + q][c];
  u32x4 p0, p1;
#pragma unroll
  for (int q = 0; q < 4; q++) {
    p0[q] = (unsigned)o[2 * q]     | ((unsigned)o[2 * q + 1] << 16);
    p1[q] = (unsigned)o[2 * q + 8] | ((unsigned)o[2 * q + 9] << 16);
  }
  unsigned short* dp = dst + (size_t)(c0 + c) * ldb + r0 + rb;
  *(u32x4*)dp = p0;
  *(u32x4*)(dp + 8) = p1;
}

// ---------------- K0: convert me/Wk + transpose Wq/Wv/Wo (all fp32 -> bf16) -------------
__global__ __launch_bounds__(256) void k_conv(
  const float* __restrict__ me, const float* __restrict__ Wq, const float* __restrict__ Wk,
  const float* __restrict__ Wv, const float* __restrict__ Wo,
  unsigned short* __restrict__ me_b, unsigned short* __restrict__ wk_b,
  unsigned short* __restrict__ wqt, unsigned short* __restrict__ wvt,
  unsigned short* __restrict__ wot)
{
  __shared__ unsigned short tile[64][72];
  const int bid = blockIdx.x, t = threadIdx.x;
  if (bid < 512) {
    for (int v = bid * 256 + t; v < 393216; v += 512 * 256) {
      const float* sp; unsigned short* dp;
      if (v < 262144) { sp = me + 4 * (size_t)v; dp = me_b + 4 * (size_t)v; }
      else { int i = v - 262144; sp = Wk + 4 * (size_t)i; dp = wk_b + 4 * (size_t)i; }
      f32x4 x = *(const f32x4*)sp;
      unsigned long long pk = (unsigned long long)((unsigned)f2bf(x[0]) | ((unsigned)f2bf(x[1]) << 16))
                            | (((unsigned long long)((unsigned)f2bf(x[2]) | ((unsigned)f2bf(x[3]) << 16))) << 32);
      *(unsigned long long*)dp = pk;
    }
    return;
  }
  if (bid < 640) {            // Wq: per head [512][128] -> [128][512]
    int idx = bid - 512, h = idx >> 4, tl = idx & 15;
    transpose_tile(Wq + (size_t)h * 65536, 128, wqt + (size_t)h * 65536, 512,
                   (tl >> 1) * 64, (tl & 1) * 64, tile);
  } else if (bid < 768) {     // Wv
    int idx = bid - 640, h = idx >> 4, tl = idx & 15;
    transpose_tile(Wv + (size_t)h * 65536, 128, wvt + (size_t)h * 65536, 512,
                   (tl >> 1) * 64, (tl & 1) * 64, tile);
  } else {                    // Wo: [1024][512] -> [512][1024]
    int idx = bid - 768;
    transpose_tile(Wo, 512, wot, 1024, (idx >> 3) * 64, (idx & 7) * 64, tile);
  }
}

// ---------------- K1: fused q+u, 64-row tiles: 512 blocks = (h 8) x (bnh 2) x (bm 32) ---
__global__ __launch_bounds__(256) void k_qu(const unsigned short* __restrict__ me_b,
                                            const unsigned short* __restrict__ wqt,
                                            const float* __restrict__ bq,
                                            const unsigned short* __restrict__ wk_b,
                                            unsigned short* __restrict__ T)
{
  __shared__ unsigned short St[2][128 * 64];   // 32 KB
  __shared__ unsigned short Qs[64 * 128];      // 16 KB
  int bid = blockIdx.x;
  int h = bid & 7, bm = bid >> 4, bnh = (bid >> 3) & 1;
  const int t = threadIdx.x, lane = t & 63, w = t >> 6;
  const int m0 = (w >> 1) * 32, n0 = (w & 1) * 64;
  f32x4 z = {0.f, 0.f, 0.f, 0.f};

  // phase 1: q tile [64x128] = me[bm*64..+64) @ wqt[h]  (K=512)
  f32x4 qacc[2][4];
#pragma unroll
  for (int i = 0; i < 2; i++) for (int j = 0; j < 4; j++) qacc[i][j] = z;
  gemm_core64(me_b + (size_t)bm * 64 * 512, 512, wqt + (size_t)h * 65536, 512, 8, St[0], St[1], qacc);

  // issue wk chunk0 loads upfront (latency covered by Qs epilogue VALU)
  const int rb_ = t >> 1, ub = (t & 1) * 4;
  u32x4 wv[2][4];
  {
    const unsigned short* gb = wk_b + (size_t)h * 65536 + (size_t)((bnh * 2) * 128 + rb_) * 128;
#pragma unroll
    for (int kt = 0; kt < 2; kt++)
#pragma unroll
      for (int q = 0; q < 4; q++)
        wv[kt][q] = *(const u32x4*)(gb + kt * 64 + (ub + q) * 8);
  }

  // write q tile (+bq, ->bf16) into Qs
#pragma unroll
  for (int i = 0; i < 2; i++)
#pragma unroll
    for (int j = 0; j < 4; j++) {
      int col = n0 + j * 16 + (lane & 15);
      float bqv = bq[h * 128 + col];
#pragma unroll
      for (int rg = 0; rg < 4; rg++) {
        int row = m0 + i * 16 + (lane >> 4) * 4 + rg;
        *(unsigned short*)((char*)Qs + row * 256 + ((((col >> 3) ^ (row & 15)) << 4)) + (col & 7) * 2)
            = f2bf(qacc[i][j][rg] + bqv);
      }
    }
  __syncthreads();   // phase1 St reads done + Qs visible

#pragma unroll
  for (int c = 0; c < 2; c++) {
    int bn = bnh * 2 + c;
    if (c) __syncthreads();   // previous chunk's St reads done
    // write staged wk chunk regs -> LDS
#pragma unroll
    for (int kt = 0; kt < 2; kt++)
#pragma unroll
      for (int q = 0; q < 4; q++)
        ((u32x4*)(St[kt] + rb_ * 64))[(ub + q) ^ (rb_ & 7)] = wv[kt][q];
    __syncthreads();
    if (c == 0) {   // issue chunk1 loads; in flight across chunk0 MFMA
      const unsigned short* gb = wk_b + (size_t)h * 65536 + (size_t)((bnh * 2 + 1) * 128 + rb_) * 128;
#pragma unroll
      for (int kt = 0; kt < 2; kt++)
#pragma unroll
        for (int q = 0; q < 4; q++)
          wv[kt][q] = *(const u32x4*)(gb + kt * 64 + (ub + q) * 8);
    }
    // u chunk [64x128] = Qs @ wk^T  (K=128)
    f32x4 acc[2][4];
#pragma unroll
    for (int i = 0; i < 2; i++) for (int j = 0; j < 4; j++) acc[i][j] = z;
#pragma unroll
    for (int kt = 0; kt < 2; kt++)
#pragma unroll
      for (int ks = 0; ks < 2; ks++) {
        s16x8 af[2], bf[4];
        int sa = ks * 4 + (lane >> 4);
        int gq = (kt * 2 + ks) * 4 + (lane >> 4);
#pragma unroll
        for (int i = 0; i < 2; i++) {
          int ra = m0 + i * 16 + (lane & 15);
          af[i] = *(const s16x8*)((char*)Qs + ra * 256 + ((gq ^ (ra & 15)) << 4));
        }
#pragma unroll
        for (int j = 0; j < 4; j++) {
          int rb = n0 + j * 16 + (lane & 15);
          bf[j] = *(const s16x8*)(St[kt] + rb * 64 + ((sa ^ (rb & 7)) << 3));
        }
#pragma unroll
        for (int i = 0; i < 2; i++)
#pragma unroll
          for (int j = 0; j < 4; j++)
            acc[i][j] = __builtin_amdgcn_mfma_f32_16x16x32_bf16(af[i], bf[j], acc[i][j], 0, 0, 0);
      }
    // scaled store
#pragma unroll
    for (int i = 0; i < 2; i++)
#pragma unroll
      for (int j = 0; j < 4; j++) {
        int col = h * 512 + bn * 128 + n0 + j * 16 + (lane & 15);
#pragma unroll
        for (int rg = 0; rg < 4; rg++) {
          int row = bm * 64 + m0 + i * 16 + (lane >> 4) * 4 + rg;
          T[(size_t)row * 4096 + col] = f2bf(acc[i][j][rg] * SCALE_INV_SQRT_H);
        }
      }
  }
}

// ---------------- K2: fused per-batch attention (1 batch/block, 2048 blocks) ------------
// All 34 global loads (T + other) issued upfront: ~8.5KB outstanding/wave for MLP.
__global__ __launch_bounds__(256) void k_attn(const float* __restrict__ other,
                                              const unsigned short* __restrict__ T,
                                              unsigned short* __restrict__ wbuf)
{
  __shared__ unsigned short oth[64 * 512];   // [n][kf] bf16, granule-XOR swizzled (64KB)
  __shared__ unsigned short t_lds[8 * 512];  // [h][kf] bf16, swizzled (8KB)
  __shared__ float s_lds[8 * 66];            // scores, padded
  __shared__ char a_raw[4 * 1056];           // 4 replicas of probs [8][64] bf16
  const int b = blockIdx.x;
  const int t = threadIdx.x, l = t & 63, w = t >> 6;

  // issue ALL loads upfront
  u32x4 tv[2];
  f32x4 ov[32];
  {
    const unsigned short* tp = T + (size_t)b * 4096 + (t >> 5) * 512 + (t & 31) * 16;
    tv[0] = *(const u32x4*)tp;
    tv[1] = *(const u32x4*)(tp + 8);
    const f32x4* gp = (const f32x4*)(other + (size_t)b * 32768 + (size_t)(t >> 2) * 512);
#pragma unroll
    for (int j = 0; j < 32; j++) ov[j] = gp[(t & 3) + j * 4];
  }
  // write T rows (8 x 512)
  {
    int row = t >> 5;
    int col0 = (t & 31) * 16;
#pragma unroll
    for (int i = 0; i < 2; i++) {
      int gr = (col0 >> 3) + i;
      *(u32x4*)((char*)t_lds + row * 1024 + ((gr ^ row) << 4)) = tv[i];
    }
  }
  // convert + write other (rm swizzled; b64 writes conflict-free)
  {
    int n = t >> 2;
    int nx = n & 7;
#pragma unroll
    for (int j = 0; j < 32; j++) {
      int kf0 = (t & 3) * 4 + j * 16;
      unsigned int lo = (unsigned)f2bf(ov[j][0]) | ((unsigned)f2bf(ov[j][1]) << 16);
      unsigned int hi = (unsigned)f2bf(ov[j][2]) | ((unsigned)f2bf(ov[j][3]) << 16);
      unsigned long long pk = (unsigned long long)lo | ((unsigned long long)hi << 32);
      int g = kf0 >> 3;
      *(unsigned long long*)((char*)oth + n * 1024 + ((g ^ nx) << 4) + (kf0 & 7) * 2) = pk;
    }
  }
  bar_lds();

  // GEMM1 (MFMA): S[h][n] = sum_kf T[h][kf] * other[n][kf]
  {
    f32x4 sacc = {0.f, 0.f, 0.f, 0.f};
    int arow = l & 7;
    int bn = w * 16 + (l & 15);
    int bx = bn & 7;
#pragma unroll
    for (int kk = 0; kk < 16; kk++) {
      int gr = kk * 4 + (l >> 4);
      s16x8 af  = *(const s16x8*)((char*)t_lds + arow * 1024 + ((gr ^ arow) << 4));
      s16x8 bfv = *(const s16x8*)((char*)oth + bn * 1024 + ((gr ^ bx) << 4));
      sacc = __builtin_amdgcn_mfma_f32_16x16x32_bf16(af, bfv, sacc, 0, 0, 0);
    }
    int hbase = (l >> 4) * 4;
    if (hbase < 8) {
#pragma unroll
      for (int rg = 0; rg < 4; rg++) s_lds[(hbase + rg) * 66 + w * 16 + (l & 15)] = sacc[rg];
    }
  }
  bar_lds();

  // softmax over n=64 per head; wave w handles heads 2w,2w+1; 4 prob replicas
#pragma unroll
  for (int hh = 0; hh < 2; hh++) {
    int h = w * 2 + hh;
    float v = s_lds[h * 66 + l];
    float mx = v;
#pragma unroll
    for (int off = 32; off > 0; off >>= 1) mx = fmaxf(mx, __shfl_xor(mx, off));
    float p = __expf(v - mx);
    float sm = p;
#pragma unroll
    for (int off = 32; off > 0; off >>= 1) sm += __shfl_xor(sm, off);
    unsigned short ab = f2bf(p / sm);
#pragma unroll
    for (int rep = 0; rep < 4; rep++)
      *(unsigned short*)(a_raw + rep * 1056 + h * 128 + l * 2) = ab;
  }
  bar_lds();

  // GEMM2 (VALU): w[h][kf] = sum_n a[h][n]*other[n][kf]
  {
    int g = l >> 4;
    int klane = l & 15;
    int kf0 = w * 128 + klane * 8;
    const char* abase = a_raw + g * 1056;
    s16x8 a0[8], a1[8];
#pragma unroll
    for (int r = 0; r < 8; r++) {
      a0[r] = *(const s16x8*)(abase + (2 * g) * 128 + r * 16);
      a1[r] = *(const s16x8*)(abase + (2 * g + 1) * 128 + r * 16);
    }
    float acc0[8], acc1[8];
#pragma unroll
    for (int q = 0; q < 8; q++) { acc0[q] = 0.f; acc1[q] = 0.f; }
    const char* obase = (const char*)oth;
    int gsl = w * 16 + klane;
#pragma unroll
    for (int r = 0; r < 8; r++) {
#pragma unroll
      for (int jj = 0; jj < 8; jj++) {
        int n = r * 8 + jj;
        float av0 = bf2f((unsigned short)a0[r][jj]);
        float av1 = bf2f((unsigned short)a1[r][jj]);
        s16x8 o = *(const s16x8*)(obase + n * 1024 + ((gsl ^ (n & 7)) << 4));
#pragma unroll
        for (int q = 0; q < 8; q++) {
          float f = bf2f((unsigned short)o[q]);
          acc0[q] += av0 * f;
          acc1[q] += av1 * f;
        }
      }
    }
    int h0 = 2 * g, h1 = h0 + 1;
    u32x4 p0, p1;
#pragma unroll
    for (int q = 0; q < 4; q++) {
      p0[q] = (unsigned)f2bf(acc0[2 * q]) | ((unsigned)f2bf(acc0[2 * q + 1]) << 16);
      p1[q] = (unsigned)f2bf(acc1[2 * q]) | ((unsigned)f2bf(acc1[2 * q + 1]) << 16);
    }
    *(u32x4*)(wbuf + ((size_t)b * 8 + h0) * 512 + kf0) = p0;
    *(u32x4*)(wbuf + ((size_t)b * 8 + h1) * 512 + kf0) = p1;
  }
}

// ---------------- K3: c, 64x64 tiles: 512 blocks = (bm 32 x dn 2) x (h 8); bid&7=h ------
__global__ __launch_bounds__(256) void k_c(const unsigned short* __restrict__ wbuf,
                                           const unsigned short* __restrict__ wvt,
                                           unsigned short* __restrict__ cbuf)
{
  __shared__ unsigned short As[64 * 64], Bs[64 * 64];
  int bid = blockIdx.x;
  int h = bid & 7, rest = bid >> 3;
  int dn = rest & 1, bm = rest >> 1;
  f32x4 acc[2][2]; f32x4 z = {0.f, 0.f, 0.f, 0.f};
#pragma unroll
  for (int i = 0; i < 2; i++) for (int j = 0; j < 2; j++) acc[i][j] = z;
  gemm_core32(wbuf + ((size_t)bm * 64 * 8 + h) * 512, 4096,
              wvt + (size_t)h * 65536 + (size_t)dn * 64 * 512, 512, 8, As, Bs, acc);
  // store 64x64 tile
  {
    const int t = threadIdx.x, lane = t & 63, w = t >> 6;
    const int m0 = (w >> 1) * 32, n0 = (w & 1) * 32;
    unsigned short* C = cbuf + (size_t)bm * 64 * 1024 + h * 128 + dn * 64;
#pragma unroll
    for (int i = 0; i < 2; i++)
#pragma unroll
      for (int j = 0; j < 2; j++) {
        int col = n0 + j * 16 + (lane & 15);
#pragma unroll
        for (int rg = 0; rg < 4; rg++) {
          int row = m0 + i * 16 + (lane >> 4) * 4 + rg;
          C[(size_t)row * 1024 + col] = f2bf(acc[i][j][rg]);
        }
      }
  }
}

// ---------------- K4: LN + ReLU + out = cn @ Wo  (fp32 out) ------------------------------
// 512 blocks = 64 bm x 8 bn (64-col tiles); Bs 8KB -> 72KB LDS -> 2 blocks/CU.
// Bs staging software-pipelined (preload next k-step's regs before MFMA).
__global__ __launch_bounds__(256) void k_out(const unsigned short* __restrict__ cbuf,
                                             const float* __restrict__ gamma,
                                             const float* __restrict__ beta,
                                             const unsigned short* __restrict__ wot,
                                             float* __restrict__ out)
{
  __shared__ unsigned short As[32 * 1024];   // 64 KB
  __shared__ unsigned short Bs[64 * 64];     //  8 KB
  int bid = blockIdx.x;
  int bm = bid >> 3, bn = bid & 7;
  const int t = threadIdx.x, lane = t & 63, w = t >> 6;
  {
    int r = t >> 3;
    const unsigned short* g = cbuf + (size_t)(bm * 32 + r) * 1024;
#pragma unroll
    for (int q = 0; q < 16; q++) {
      int u = (t & 7) + q * 8;
      u32x4 v = *(const u32x4*)(g + u * 8);
      ((u32x4*)(As + r * 1024))[u ^ (r & 7)] = v;
    }
  }
  float gv[16], bv[16];
#pragma unroll
  for (int si = 0; si < 2; si++)
#pragma unroll
    for (int j = 0; j < 8; j++) {
      int k = (lane + si * 64) * 8 + j;
      gv[si * 8 + j] = gamma[k];
      bv[si * 8 + j] = beta[k];
    }
  __syncthreads();
  for (int rr = 0; rr < 8; rr++) {
    int r = w * 8 + rr;
    float vals[16]; float sum = 0.f, sq = 0.f;
#pragma unroll
    for (int si = 0; si < 2; si++) {
      int s = lane + si * 64;
      s16x8 pv = *(const s16x8*)(As + r * 1024 + ((s ^ (r & 7)) << 3));
#pragma unroll
      for (int j = 0; j < 8; j++) { float f = bf2f((unsigned short)pv[j]); vals[si * 8 + j] = f; sum += f; sq += f * f; }
    }
#pragma unroll
    for (int off = 32; off > 0; off >>= 1) { sum += __shfl_xor(sum, off); sq += __shfl_xor(sq, off); }
    float mu = sum * (1.f / 1024.f);
    float var = sq * (1.f / 1024.f) - mu * mu;
    float rs = rsqrtf(var + 1e-5f);
#pragma unroll
    for (int si = 0; si < 2; si++) {
      int s = lane + si * 64;
      unsigned short o[8];
#pragma unroll
      for (int j = 0; j < 8; j++) {
        float f = (vals[si * 8 + j] - mu) * rs * gv[si * 8 + j] + bv[si * 8 + j];
        o[j] = f2bf(fmaxf(f, 0.f));
      }
      u32x4 pk;
      pk[0] = (unsigned)o[0] | ((unsigned)o[1] << 16);
      pk[1] = (unsigned)o[2] | ((unsigned)o[3] << 16);
      pk[2] = (unsigned)o[4] | ((unsigned)o[5] << 16);
      pk[3] = (unsigned)o[6] | ((unsigned)o[7] << 16);
      ((u32x4*)(As + r * 1024))[s ^ (r & 7)] = pk;
    }
  }
  // GEMM: out_tile[32x64] = cn_tile @ Wo_t(bn), K=1024, pipelined Bs staging
  const int wm = w >> 1, wn = w & 1;
  f32x4 acc[2]; f32x4 z = {0.f, 0.f, 0.f, 0.f};
#pragma unroll
  for (int j = 0; j < 2; j++) acc[j] = z;
  const unsigned short* Bg = wot + (size_t)bn * 64 * 1024;
  const int rB = t >> 2, uB = (t & 3) * 2;
  u32x4 pv[2];
#pragma unroll
  for (int q = 0; q < 2; q++)
    pv[q] = *(const u32x4*)(Bg + (size_t)rB * 1024 + (uB + q) * 8);
  for (int kk = 0; kk < 16; kk++) {
    __syncthreads();
#pragma unroll
    for (int q = 0; q < 2; q++)
      ((u32x4*)(Bs + rB * 64))[(uB + q) ^ (rB & 7)] = pv[q];
    __syncthreads();
    if (kk < 15) {
#pragma unroll
      for (int q = 0; q < 2; q++)
        pv[q] = *(const u32x4*)(Bg + (size_t)rB * 1024 + (kk + 1) * 64 + (uB + q) * 8);
    }
#pragma unroll
    for (int ks = 0; ks < 2; ks++) {
      int ra = wm * 16 + (lane & 15);
      int sa = kk * 8 + ks * 4 + (lane >> 4);
      s16x8 af = *(const s16x8*)(As + ra * 1024 + ((sa ^ (ra & 7)) << 3));
      int sb = ks * 4 + (lane >> 4);
#pragma unroll
      for (int j = 0; j < 2; j++) {
        int rb = wn * 32 + j * 16 + (lane & 15);
        s16x8 bfv = *(const s16x8*)(Bs + rb * 64 + ((sb ^ (rb & 7)) << 3));
        acc[j] = __builtin_amdgcn_mfma_f32_16x16x32_bf16(af, bfv, acc[j], 0, 0, 0);
      }
    }
  }
#pragma unroll
  for (int j = 0; j < 2; j++) {
    int col = bn * 64 + wn * 32 + j * 16 + (lane & 15);
#pragma unroll
    for (int rg = 0; rg < 4; rg++) {
      int row = bm * 32 + wm * 16 + (lane >> 4) * 4 + rg;
      out[(size_t)row * 512 + col] = acc[j][rg];
    }
  }
}

// -----------------------------------------------------------------------------------------
extern "C" void kernel_launch(void* const* d_in, const int* in_sizes, int n_in,
                              void* d_out, int out_size, void* d_ws, size_t ws_size,
                              hipStream_t stream)
{
  (void)in_sizes; (void)n_in; (void)out_size;
  const float* me    = (const float*)d_in[0];
  const float* other = (const float*)d_in[1];
  const float* Wq    = (const float*)d_in[2];
  const float* bq    = (const float*)d_in[3];
  const float* Wk    = (const float*)d_in[4];
  const float* Wv    = (const float*)d_in[5];
  const float* gamma = (const float*)d_in[6];
  const float* beta  = (const float*)d_in[7];
  const float* Wo    = (const float*)d_in[8];
  float* out = (float*)d_out;
  char* ws = (char*)d_ws;

  unsigned short* me_b = (unsigned short*)(ws + 0);          //  2 MB
  unsigned short* wk_b = (unsigned short*)(ws + 2097152);    //  1 MB
  unsigned short* wqt  = (unsigned short*)(ws + 3145728);    //  1 MB
  unsigned short* wvt  = (unsigned short*)(ws + 4194304);    //  1 MB
  unsigned short* wot  = (unsigned short*)(ws + 5242880);    //  1 MB
  unsigned short* T_b  = (unsigned short*)(ws + 10485760);   // 16 MB
  unsigned short* w_b  = (unsigned short*)(ws + 27262976);   // 16 MB
  unsigned short* c_b  = (unsigned short*)(ws + 44040192);   //  4 MB
  if (ws_size < 48234496) return;

  k_conv<<<dim3(896),  dim3(256), 0, stream>>>(me, Wq, Wk, Wv, Wo, me_b, wk_b, wqt, wvt, wot);
  k_qu  <<<dim3(512),  dim3(256), 0, stream>>>(me_b, wqt, bq, wk_b, T_b);
  k_attn<<<dim3(2048), dim3(256), 0, stream>>>(other, T_b, w_b);
  k_c   <<<dim3(512),  dim3(256), 0, stream>>>(w_b, wvt, c_b);
  k_out <<<dim3(512),  dim3(256), 0, stream>>>(c_b, gamma, beta, wot, out);
}